// Round 1
// baseline (595.758 us; speedup 1.0000x reference)
//
#include <hip/hip_runtime.h>
#include <stdint.h>

#define NB 2
#define NC 34
#define HH 512
#define WW 1024
#define HWW (HH*WW)
#define KK 200
#define PADR 3
#define CAP 32768
#define NBIN 256
#define MCAP 4096

// ---------------------------------------------------------------- init ws
__global__ void __launch_bounds__(256) k_init(uint32_t* cnt, uint32_t* hist,
                                              uint32_t* counts, float* sums) {
    int t = blockIdx.x * 256 + threadIdx.x;
    if (t < NB) cnt[t] = 0u;
    if (t < NB * NBIN) hist[t] = 0u;
    if (t < NB * (KK + 1) * NC) counts[t] = 0u;
    if (t < NB * (KK + 1)) sums[t] = 0.f;
}

// ------------------------------------------- per-pixel argmax + softmax stats
__global__ void __launch_bounds__(256) k_seg(const float* __restrict__ logits,
                                             float* __restrict__ segs_out,
                                             float* __restrict__ smax,
                                             float* __restrict__ sden,
                                             int use_stats) {
    int t = blockIdx.x * 256 + threadIdx.x;   // t < NB*HWW/2
    if (t >= NB * HWW / 2) return;
    int p = t * 2;
    int b = p / HWW, r = p - b * HWW;
    const float* base = logits + (size_t)b * NC * HWW + r;
    float2 v[NC];
    float m0 = -3e38f, m1 = -3e38f;
    int a0 = 0, a1 = 0;
#pragma unroll
    for (int c = 0; c < NC; ++c) {
        v[c] = *(const float2*)(base + (size_t)c * HWW);
        if (v[c].x > m0) { m0 = v[c].x; a0 = c; }
        if (v[c].y > m1) { m1 = v[c].y; a1 = c; }
    }
    float s0 = 0.f, s1 = 0.f;
#pragma unroll
    for (int c = 0; c < NC; ++c) {
        s0 += __expf(v[c].x - m0);
        s1 += __expf(v[c].y - m1);
    }
    *(float2*)(segs_out + p) = make_float2((float)a0, (float)a1);
    if (use_stats) {
        *(float2*)(smax + p) = make_float2(m0, m1);
        *(float2*)(sden + p) = make_float2(s0, s1);
    }
}

// ------------------------------------------------- NMS candidates + histogram
__global__ void __launch_bounds__(256) k_nms(const float* __restrict__ cmap,
                                             uint64_t* __restrict__ cand,
                                             uint32_t* __restrict__ cnt,
                                             uint32_t* __restrict__ hist) {
    int p = blockIdx.x * 256 + threadIdx.x;
    if (p >= NB * HWW) return;
    int b = p / HWW, r = p - b * HWW;
    int h = r / WW, w = r - h * WW;
    float cv = cmap[p];
    const float* bb = cmap + (size_t)b * HWW;
    int h0 = h - PADR < 0 ? 0 : h - PADR;
    int h1 = h + PADR > HH - 1 ? HH - 1 : h + PADR;
    int w0 = w - PADR < 0 ? 0 : w - PADR;
    int w1 = w + PADR > WW - 1 ? WW - 1 : w + PADR;
    float m = -3e38f;
    for (int hh = h0; hh <= h1; ++hh)
        for (int ww = w0; ww <= w1; ++ww)
            m = fmaxf(m, bb[hh * WW + ww]);
    // candidate iff pooled > 0.1 and center == pooled (center is local max)
    if (m > 0.1f && cv == m) {
        uint32_t pos = atomicAdd(&cnt[b], 1u);
        if (pos < CAP) {
            uint32_t bits = __float_as_uint(cv);
            cand[(size_t)b * CAP + pos] =
                ((uint64_t)bits << 32) | (uint64_t)(0xFFFFFFFFu - (uint32_t)r);
        }
        int bin = (int)(cv * 256.0f);
        if (bin > 255) bin = 255;
        if (bin < 0) bin = 0;
        atomicAdd(&hist[b * NBIN + bin], 1u);
    }
}

// ------------------------------------------------- exact top-K with ordering
__global__ void __launch_bounds__(256) k_topk(const uint64_t* __restrict__ cand,
                                              const uint32_t* __restrict__ cnt,
                                              const uint32_t* __restrict__ hist,
                                              float* __restrict__ probs_out,
                                              float* __restrict__ cxy) {
    int b = blockIdx.x;
    int tid = threadIdx.x;
    __shared__ uint64_t lkey[MCAP];
    __shared__ uint32_t lhist[NBIN];
    __shared__ uint32_t lM;
    __shared__ float Tv;
    if (tid < NBIN) lhist[tid] = hist[b * NBIN + tid];
    if (tid == 0) lM = 0u;
    __syncthreads();
    if (tid == 0) {
        uint32_t cum = 0;
        int bstar = 0;
        for (int i = NBIN - 1; i >= 0; --i) {
            cum += lhist[i];
            if (cum >= KK) { bstar = i; break; }
        }
        Tv = (float)bstar / 256.0f;   // exact (power of two)
    }
    // init all K slots (slots with rank >= #candidates stay at these values)
    if (tid < KK) {
        probs_out[b * KK + tid] = 0.f;
        cxy[(b * KK + tid) * 2]     = 1e19f;  // invalid -> huge coords -> inf dist
        cxy[(b * KK + tid) * 2 + 1] = 1e19f;
    }
    __syncthreads();
    uint32_t N = cnt[b];
    if (N > CAP) N = CAP;
    float tv = Tv;
    for (uint32_t i = tid; i < N; i += 256) {
        uint64_t kk = cand[(size_t)b * CAP + i];
        float v = __uint_as_float((uint32_t)(kk >> 32));
        if (v >= tv) {
            uint32_t pos = atomicAdd(&lM, 1u);
            if (pos < MCAP) lkey[pos] = kk;
        }
    }
    __syncthreads();
    uint32_t M = lM;
    if (M > MCAP) M = MCAP;
    // exact global rank among kept candidates (all dropped ones are strictly smaller)
    for (uint32_t i = tid; i < M; i += 256) {
        uint64_t kk = lkey[i];
        uint32_t rank = 0;
        for (uint32_t j = 0; j < M; ++j) rank += (lkey[j] > kk) ? 1u : 0u;
        if (rank < KK) {
            uint32_t bits = (uint32_t)(kk >> 32);
            uint32_t idx = 0xFFFFFFFFu - (uint32_t)(kk & 0xFFFFFFFFull);
            probs_out[b * KK + rank] = __uint_as_float(bits);
            cxy[(b * KK + rank) * 2]     = (float)(idx % WW);
            cxy[(b * KK + rank) * 2 + 1] = (float)(idx / WW);
        }
    }
}

// ---------------------------------------- closest-center argmin + counts hist
__global__ void __launch_bounds__(256) k_assign(const float* __restrict__ reg,
                                                const float* __restrict__ cxy,
                                                const float* __restrict__ segsf,
                                                float* __restrict__ closest_out,
                                                uint32_t* __restrict__ counts) {
    __shared__ float2 cc[KK];
    int p0 = blockIdx.x * 256;
    int b = p0 / HWW;
    int tid = threadIdx.x;
    if (tid < KK) cc[tid] = ((const float2*)cxy)[b * KK + tid];
    __syncthreads();
    int p = p0 + tid;
    int r = p - b * HWW;
    int h = r / WW, w = r - h * WW;
    float rx = reg[(size_t)b * 2 * HWW + r];
    float ry = reg[(size_t)b * 2 * HWW + HWW + r];
    float px = (float)(w + 1) - rx;
    float py = (float)(h + 1) - ry;
    float best = __builtin_inff();
    int bk = 0;
#pragma unroll 4
    for (int k = 0; k < KK; ++k) {
        float2 c = cc[k];
        float dx = __fsub_rn(px, c.x);
        float dy = __fsub_rn(py, c.y);
        float d2 = __fadd_rn(__fmul_rn(dx, dx), __fmul_rn(dy, dy));  // no fma, match ref
        if (d2 < best) { best = d2; bk = k; }   // strict < : first-occurrence argmin
    }
    closest_out[p] = (float)(bk + 1);
    int seg = (int)segsf[p];
    if (seg >= 24 && seg <= 33) {
        atomicAdd(&counts[(b * (KK + 1) + (bk + 1)) * NC + seg], 1u);
    }
}

// ---------------------------------------- per-instance majority class, n, valid
__global__ void __launch_bounds__(256) k_inst(const uint32_t* __restrict__ counts,
                                              const float* __restrict__ probs_out,
                                              float* __restrict__ ic_out,
                                              float* __restrict__ np_out,
                                              float* __restrict__ va_out) {
    int t = blockIdx.x * 256 + threadIdx.x;
    if (t >= NB * KK) return;
    int b = t / KK, k = t - b * KK;
    const uint32_t* row = counts + (size_t)(b * (KK + 1) + (k + 1)) * NC;
    uint32_t n = 0, mx = 0;
    int am = 0;
#pragma unroll
    for (int c = 0; c < NC; ++c) {
        uint32_t x = row[c];
        n += x;
        if (x > mx) { mx = x; am = c; }   // first-occurrence argmax
    }
    ic_out[t] = (float)am;
    np_out[t] = (float)n;
    va_out[t] = (n > 0u && probs_out[t] > 0.f) ? 1.f : 0.f;
}

// ---------------------------------------- per-instance softmax-prob sums
template <int USE_STATS>
__global__ void __launch_bounds__(256) k_sums(const float* __restrict__ logits,
                                              const float* __restrict__ segsf,
                                              const float* __restrict__ closestf,
                                              const float* __restrict__ icf,
                                              const float* __restrict__ smax,
                                              const float* __restrict__ sden,
                                              float* __restrict__ sums) {
    __shared__ int ic_l[KK];
    __shared__ float psum[KK + 1];
    int tid = threadIdx.x;
    int p0 = blockIdx.x * 256;
    int b = p0 / HWW;
    if (tid < KK) ic_l[tid] = (int)icf[b * KK + tid];
    if (tid < KK + 1) psum[tid] = 0.f;
    __syncthreads();
    int p = p0 + tid;
    int r = p - b * HWW;
    int seg = (int)segsf[p];
    if (seg >= 24 && seg <= 33) {
        int cl = (int)closestf[p];
        int ic = ic_l[cl - 1];
        const float* base = logits + (size_t)b * NC * HWW + r;
        float pr;
        if (USE_STATS) {
            float vmax = smax[p], den = sden[p];
            float lv = base[(size_t)ic * HWW];
            pr = __expf(lv - vmax) / den;
        } else {
            float v[NC];
            float vmax = -3e38f, lv = 0.f;
#pragma unroll
            for (int c = 0; c < NC; ++c) {
                v[c] = base[(size_t)c * HWW];
                vmax = fmaxf(vmax, v[c]);
                if (c == ic) lv = v[c];
            }
            float s = 0.f;
#pragma unroll
            for (int c = 0; c < NC; ++c) s += __expf(v[c] - vmax);
            pr = __expf(lv - vmax) / s;
        }
        atomicAdd(&psum[cl], pr);
    }
    __syncthreads();
    if (tid < KK + 1) {
        float x = psum[tid];
        if (x != 0.f) atomicAdd(&sums[b * (KK + 1) + tid], x);
    }
}

// ---------------------------------------- final seg_prob
__global__ void __launch_bounds__(256) k_segprob(const float* __restrict__ sums,
                                                 const float* __restrict__ np_out,
                                                 float* __restrict__ sp_out) {
    int t = blockIdx.x * 256 + threadIdx.x;
    if (t >= NB * KK) return;
    int b = t / KK, k = t - b * KK;
    float n = np_out[t];
    float s = sums[b * (KK + 1) + k + 1];
    sp_out[t] = (n > 0.f) ? (s / n) : 0.f;
}

extern "C" void kernel_launch(void* const* d_in, const int* in_sizes, int n_in,
                              void* d_out, int out_size, void* d_ws, size_t ws_size,
                              hipStream_t stream) {
    const float* logits = (const float*)d_in[0];
    const float* cmap   = (const float*)d_in[1];
    const float* reg    = (const float*)d_in[2];
    float* out = (float*)d_out;
    float* o_ic   = out;
    float* o_prob = out + NB * KK;
    float* o_sp   = out + 2 * NB * KK;
    float* o_np   = out + 3 * NB * KK;
    float* o_va   = out + 4 * NB * KK;
    float* o_segs = out + 5 * NB * KK;
    float* o_clo  = out + 5 * NB * KK + NB * HWW;

    char* w = (char*)d_ws;
    size_t off = 0;
    auto alloc = [&](size_t bytes) {
        off = (off + 15) & ~((size_t)15);
        void* p = w + off;
        off += bytes;
        return p;
    };
    uint64_t* cand   = (uint64_t*)alloc(sizeof(uint64_t) * NB * CAP);
    uint32_t* cnt    = (uint32_t*)alloc(sizeof(uint32_t) * NB);
    uint32_t* hist   = (uint32_t*)alloc(sizeof(uint32_t) * NB * NBIN);
    uint32_t* counts = (uint32_t*)alloc(sizeof(uint32_t) * NB * (KK + 1) * NC);
    float* sums      = (float*)alloc(sizeof(float) * NB * (KK + 1));
    float* cxy       = (float*)alloc(sizeof(float) * NB * KK * 2);
    size_t base_need = (off + 15) & ~((size_t)15);
    float* smax = (float*)(w + base_need);
    float* sden = smax + (size_t)NB * HWW;
    int use_stats = (base_need + sizeof(float) * 2 * (size_t)NB * HWW) <= ws_size ? 1 : 0;

    k_init<<<(NB * (KK + 1) * NC + 255) / 256, 256, 0, stream>>>(cnt, hist, counts, sums);
    k_seg<<<NB * HWW / 2 / 256, 256, 0, stream>>>(logits, o_segs, smax, sden, use_stats);
    k_nms<<<NB * HWW / 256, 256, 0, stream>>>(cmap, cand, cnt, hist);
    k_topk<<<NB, 256, 0, stream>>>(cand, cnt, hist, o_prob, cxy);
    k_assign<<<NB * HWW / 256, 256, 0, stream>>>(reg, cxy, o_segs, o_clo, counts);
    k_inst<<<(NB * KK + 255) / 256, 256, 0, stream>>>(counts, o_prob, o_ic, o_np, o_va);
    if (use_stats)
        k_sums<1><<<NB * HWW / 256, 256, 0, stream>>>(logits, o_segs, o_clo, o_ic, smax, sden, sums);
    else
        k_sums<0><<<NB * HWW / 256, 256, 0, stream>>>(logits, o_segs, o_clo, o_ic, smax, sden, sums);
    k_segprob<<<(NB * KK + 255) / 256, 256, 0, stream>>>(sums, o_np, o_sp);
}

// Round 2
// 488.793 us; speedup vs baseline: 1.2188x; 1.2188x over previous
//
#include <hip/hip_runtime.h>
#include <stdint.h>

#define NB 2
#define NC 34
#define HH 512
#define WW 1024
#define HWW (HH*WW)
#define KK 200
#define CAP 32768
#define NBIN 256
#define MCAP 4096

// NMS tiling
#define TW 128
#define TH 16
#define HALO 3

// ---------------------------------------------------------------- init ws
__global__ void __launch_bounds__(256) k_init(uint32_t* cnt, uint32_t* hist,
                                              uint32_t* counts, float* sums) {
    int t = blockIdx.x * 256 + threadIdx.x;
    if (t < NB) cnt[t] = 0u;
    if (t < NB * NBIN) hist[t] = 0u;
    if (t < NB * (KK + 1) * NC) counts[t] = 0u;
    if (t < NB * (KK + 1)) sums[t] = 0.f;
}

// ------------------------------------------- per-pixel argmax + softmax stats
__global__ void __launch_bounds__(256) k_seg(const float* __restrict__ logits,
                                             float* __restrict__ segs_out,
                                             float* __restrict__ smax,
                                             float* __restrict__ sden,
                                             int use_stats) {
    int t = blockIdx.x * 256 + threadIdx.x;   // t < NB*HWW/2
    if (t >= NB * HWW / 2) return;
    int p = t * 2;
    int b = p / HWW, r = p - b * HWW;
    const float* base = logits + (size_t)b * NC * HWW + r;
    float2 v[NC];
    float m0 = -3e38f, m1 = -3e38f;
    int a0 = 0, a1 = 0;
#pragma unroll
    for (int c = 0; c < NC; ++c) {
        v[c] = *(const float2*)(base + (size_t)c * HWW);
        if (v[c].x > m0) { m0 = v[c].x; a0 = c; }
        if (v[c].y > m1) { m1 = v[c].y; a1 = c; }
    }
    float s0 = 0.f, s1 = 0.f;
#pragma unroll
    for (int c = 0; c < NC; ++c) {
        s0 += __expf(v[c].x - m0);
        s1 += __expf(v[c].y - m1);
    }
    *(float2*)(segs_out + p) = make_float2((float)a0, (float)a1);
    if (use_stats) {
        *(float2*)(smax + p) = make_float2(m0, m1);
        *(float2*)(sden + p) = make_float2(s0, s1);
    }
}

// ------------------------------------------------- NMS: separable 7x7 max via LDS
__global__ void __launch_bounds__(256) k_nms(const float* __restrict__ cmap,
                                             uint64_t* __restrict__ cand,
                                             uint32_t* __restrict__ cnt,
                                             uint32_t* __restrict__ hist) {
    __shared__ float sIn[TH + 2 * HALO][TW + 2 * HALO];   // 22 x 134
    __shared__ float sH[TH + 2 * HALO][TW];               // 22 x 128
    int t = blockIdx.x;
    int bx = t & (WW / TW - 1);          // 0..7
    int by = (t >> 3) & (HH / TH - 1);   // 0..31
    int b = t >> 8;                      // 0..NB-1
    int tid = threadIdx.x;
    const float* bb = cmap + (size_t)b * HWW;

    // load halo'd tile (coalesced along rows), -inf outside
    const int LW = TW + 2 * HALO;                 // 134
    const int LH = TH + 2 * HALO;                 // 22
    for (int idx = tid; idx < LW * LH; idx += 256) {
        int r = idx / LW, c = idx - r * LW;
        int gh = by * TH + r - HALO;
        int gw = bx * TW + c - HALO;
        float v = -3e38f;
        if (gh >= 0 && gh < HH && gw >= 0 && gw < WW) v = bb[gh * WW + gw];
        sIn[r][c] = v;
    }
    __syncthreads();

    // horizontal 1x7 max
    for (int idx = tid; idx < LH * TW; idx += 256) {
        int r = idx / TW, c = idx - r * TW;
        float a0 = sIn[r][c];
        float a1 = sIn[r][c + 1];
        float a2 = sIn[r][c + 2];
        float a3 = sIn[r][c + 3];
        float a4 = sIn[r][c + 4];
        float a5 = sIn[r][c + 5];
        float a6 = sIn[r][c + 6];
        float m = fmaxf(fmaxf(fmaxf(a0, a1), fmaxf(a2, a3)),
                        fmaxf(fmaxf(a4, a5), a6));
        sH[r][c] = m;
    }
    __syncthreads();

    // vertical 7x1 max + candidate test
    for (int idx = tid; idx < TH * TW; idx += 256) {
        int r = idx >> 7, c = idx & (TW - 1);
        float cv = sIn[r + HALO][c + HALO];
        float m = fmaxf(fmaxf(fmaxf(sH[r][c], sH[r + 1][c]),
                              fmaxf(sH[r + 2][c], sH[r + 3][c])),
                        fmaxf(fmaxf(sH[r + 4][c], sH[r + 5][c]), sH[r + 6][c]));
        if (m > 0.1f && cv == m) {
            int gh = by * TH + r;
            int gw = bx * TW + c;
            uint32_t rr = (uint32_t)(gh * WW + gw);
            uint32_t pos = atomicAdd(&cnt[b], 1u);
            if (pos < CAP) {
                uint32_t bits = __float_as_uint(cv);
                cand[(size_t)b * CAP + pos] =
                    ((uint64_t)bits << 32) | (uint64_t)(0xFFFFFFFFu - rr);
            }
            int bin = (int)(cv * 256.0f);
            if (bin > 255) bin = 255;
            if (bin < 0) bin = 0;
            atomicAdd(&hist[b * NBIN + bin], 1u);
        }
    }
}

// ------------------------------------------------- exact top-K with ordering
__global__ void __launch_bounds__(256) k_topk(const uint64_t* __restrict__ cand,
                                              const uint32_t* __restrict__ cnt,
                                              const uint32_t* __restrict__ hist,
                                              float* __restrict__ probs_out,
                                              float* __restrict__ cxy) {
    int b = blockIdx.x;
    int tid = threadIdx.x;
    __shared__ uint64_t lkey[MCAP];
    __shared__ uint32_t lhist[NBIN];
    __shared__ uint32_t lM;
    __shared__ float Tv;
    if (tid < NBIN) lhist[tid] = hist[b * NBIN + tid];
    if (tid == 0) lM = 0u;
    __syncthreads();
    if (tid == 0) {
        uint32_t cum = 0;
        int bstar = 0;
        for (int i = NBIN - 1; i >= 0; --i) {
            cum += lhist[i];
            if (cum >= KK) { bstar = i; break; }
        }
        Tv = (float)bstar / 256.0f;   // exact (power of two)
    }
    // init all K slots (slots with rank >= #candidates stay at these values)
    if (tid < KK) {
        probs_out[b * KK + tid] = 0.f;
        cxy[(b * KK + tid) * 2]     = 1e19f;  // invalid -> huge coords -> inf dist
        cxy[(b * KK + tid) * 2 + 1] = 1e19f;
    }
    __syncthreads();
    uint32_t N = cnt[b];
    if (N > CAP) N = CAP;
    float tv = Tv;
    for (uint32_t i = tid; i < N; i += 256) {
        uint64_t kk = cand[(size_t)b * CAP + i];
        float v = __uint_as_float((uint32_t)(kk >> 32));
        if (v >= tv) {
            uint32_t pos = atomicAdd(&lM, 1u);
            if (pos < MCAP) lkey[pos] = kk;
        }
    }
    __syncthreads();
    uint32_t M = lM;
    if (M > MCAP) M = MCAP;
    // exact global rank among kept candidates (all dropped ones are strictly smaller)
    for (uint32_t i = tid; i < M; i += 256) {
        uint64_t kk = lkey[i];
        uint32_t rank = 0;
        for (uint32_t j = 0; j < M; ++j) rank += (lkey[j] > kk) ? 1u : 0u;
        if (rank < KK) {
            uint32_t bits = (uint32_t)(kk >> 32);
            uint32_t idx = 0xFFFFFFFFu - (uint32_t)(kk & 0xFFFFFFFFull);
            probs_out[b * KK + rank] = __uint_as_float(bits);
            cxy[(b * KK + rank) * 2]     = (float)(idx % WW);
            cxy[(b * KK + rank) * 2 + 1] = (float)(idx / WW);
        }
    }
}

// ---------------------------------------- closest-center argmin + counts hist
__global__ void __launch_bounds__(256) k_assign(const float* __restrict__ reg,
                                                const float* __restrict__ cxy,
                                                const float* __restrict__ segsf,
                                                float* __restrict__ closest_out,
                                                uint32_t* __restrict__ counts) {
    __shared__ float2 cc[KK];
    int p0 = blockIdx.x * 256;
    int b = p0 / HWW;
    int tid = threadIdx.x;
    if (tid < KK) cc[tid] = ((const float2*)cxy)[b * KK + tid];
    __syncthreads();
    int p = p0 + tid;
    int r = p - b * HWW;
    int h = r / WW, w = r - h * WW;
    float rx = reg[(size_t)b * 2 * HWW + r];
    float ry = reg[(size_t)b * 2 * HWW + HWW + r];
    float px = (float)(w + 1) - rx;
    float py = (float)(h + 1) - ry;
    float best = __builtin_inff();
    int bk = 0;
#pragma unroll 4
    for (int k = 0; k < KK; ++k) {
        float2 c = cc[k];
        float dx = __fsub_rn(px, c.x);
        float dy = __fsub_rn(py, c.y);
        float d2 = __fadd_rn(__fmul_rn(dx, dx), __fmul_rn(dy, dy));  // no fma, match ref
        if (d2 < best) { best = d2; bk = k; }   // strict < : first-occurrence argmin
    }
    closest_out[p] = (float)(bk + 1);
    int seg = (int)segsf[p];
    if (seg >= 24 && seg <= 33) {
        atomicAdd(&counts[(b * (KK + 1) + (bk + 1)) * NC + seg], 1u);
    }
}

// ---------------------------------------- per-instance majority class, n, valid
__global__ void __launch_bounds__(256) k_inst(const uint32_t* __restrict__ counts,
                                              const float* __restrict__ probs_out,
                                              float* __restrict__ ic_out,
                                              float* __restrict__ np_out,
                                              float* __restrict__ va_out) {
    int t = blockIdx.x * 256 + threadIdx.x;
    if (t >= NB * KK) return;
    int b = t / KK, k = t - b * KK;
    const uint32_t* row = counts + (size_t)(b * (KK + 1) + (k + 1)) * NC;
    uint32_t n = 0, mx = 0;
    int am = 0;
#pragma unroll
    for (int c = 0; c < NC; ++c) {
        uint32_t x = row[c];
        n += x;
        if (x > mx) { mx = x; am = c; }   // first-occurrence argmax
    }
    ic_out[t] = (float)am;
    np_out[t] = (float)n;
    va_out[t] = (n > 0u && probs_out[t] > 0.f) ? 1.f : 0.f;
}

// ---------------------------------------- per-instance softmax-prob sums
template <int USE_STATS>
__global__ void __launch_bounds__(256) k_sums(const float* __restrict__ logits,
                                              const float* __restrict__ segsf,
                                              const float* __restrict__ closestf,
                                              const float* __restrict__ icf,
                                              const float* __restrict__ smax,
                                              const float* __restrict__ sden,
                                              float* __restrict__ sums) {
    __shared__ int ic_l[KK];
    __shared__ float psum[KK + 1];
    int tid = threadIdx.x;
    int p0 = blockIdx.x * 256;
    int b = p0 / HWW;
    if (tid < KK) ic_l[tid] = (int)icf[b * KK + tid];
    if (tid < KK + 1) psum[tid] = 0.f;
    __syncthreads();
    int p = p0 + tid;
    int r = p - b * HWW;
    int seg = (int)segsf[p];
    if (seg >= 24 && seg <= 33) {
        int cl = (int)closestf[p];
        int ic = ic_l[cl - 1];
        const float* base = logits + (size_t)b * NC * HWW + r;
        float pr;
        if (USE_STATS) {
            float vmax = smax[p], den = sden[p];
            float lv = base[(size_t)ic * HWW];
            pr = __expf(lv - vmax) / den;
        } else {
            float v[NC];
            float vmax = -3e38f, lv = 0.f;
#pragma unroll
            for (int c = 0; c < NC; ++c) {
                v[c] = base[(size_t)c * HWW];
                vmax = fmaxf(vmax, v[c]);
                if (c == ic) lv = v[c];
            }
            float s = 0.f;
#pragma unroll
            for (int c = 0; c < NC; ++c) s += __expf(v[c] - vmax);
            pr = __expf(lv - vmax) / s;
        }
        atomicAdd(&psum[cl], pr);
    }
    __syncthreads();
    if (tid < KK + 1) {
        float x = psum[tid];
        if (x != 0.f) atomicAdd(&sums[b * (KK + 1) + tid], x);
    }
}

// ---------------------------------------- final seg_prob
__global__ void __launch_bounds__(256) k_segprob(const float* __restrict__ sums,
                                                 const float* __restrict__ np_out,
                                                 float* __restrict__ sp_out) {
    int t = blockIdx.x * 256 + threadIdx.x;
    if (t >= NB * KK) return;
    int b = t / KK, k = t - b * KK;
    float n = np_out[t];
    float s = sums[b * (KK + 1) + k + 1];
    sp_out[t] = (n > 0.f) ? (s / n) : 0.f;
}

extern "C" void kernel_launch(void* const* d_in, const int* in_sizes, int n_in,
                              void* d_out, int out_size, void* d_ws, size_t ws_size,
                              hipStream_t stream) {
    const float* logits = (const float*)d_in[0];
    const float* cmap   = (const float*)d_in[1];
    const float* reg    = (const float*)d_in[2];
    float* out = (float*)d_out;
    float* o_ic   = out;
    float* o_prob = out + NB * KK;
    float* o_sp   = out + 2 * NB * KK;
    float* o_np   = out + 3 * NB * KK;
    float* o_va   = out + 4 * NB * KK;
    float* o_segs = out + 5 * NB * KK;
    float* o_clo  = out + 5 * NB * KK + NB * HWW;

    char* w = (char*)d_ws;
    size_t off = 0;
    auto alloc = [&](size_t bytes) {
        off = (off + 15) & ~((size_t)15);
        void* p = w + off;
        off += bytes;
        return p;
    };
    uint64_t* cand   = (uint64_t*)alloc(sizeof(uint64_t) * NB * CAP);
    uint32_t* cnt    = (uint32_t*)alloc(sizeof(uint32_t) * NB);
    uint32_t* hist   = (uint32_t*)alloc(sizeof(uint32_t) * NB * NBIN);
    uint32_t* counts = (uint32_t*)alloc(sizeof(uint32_t) * NB * (KK + 1) * NC);
    float* sums      = (float*)alloc(sizeof(float) * NB * (KK + 1));
    float* cxy       = (float*)alloc(sizeof(float) * NB * KK * 2);
    size_t base_need = (off + 15) & ~((size_t)15);
    float* smax = (float*)(w + base_need);
    float* sden = smax + (size_t)NB * HWW;
    int use_stats = (base_need + sizeof(float) * 2 * (size_t)NB * HWW) <= ws_size ? 1 : 0;

    k_init<<<(NB * (KK + 1) * NC + 255) / 256, 256, 0, stream>>>(cnt, hist, counts, sums);
    k_seg<<<NB * HWW / 2 / 256, 256, 0, stream>>>(logits, o_segs, smax, sden, use_stats);
    k_nms<<<NB * (HH / TH) * (WW / TW), 256, 0, stream>>>(cmap, cand, cnt, hist);
    k_topk<<<NB, 256, 0, stream>>>(cand, cnt, hist, o_prob, cxy);
    k_assign<<<NB * HWW / 256, 256, 0, stream>>>(reg, cxy, o_segs, o_clo, counts);
    k_inst<<<(NB * KK + 255) / 256, 256, 0, stream>>>(counts, o_prob, o_ic, o_np, o_va);
    if (use_stats)
        k_sums<1><<<NB * HWW / 256, 256, 0, stream>>>(logits, o_segs, o_clo, o_ic, smax, sden, sums);
    else
        k_sums<0><<<NB * HWW / 256, 256, 0, stream>>>(logits, o_segs, o_clo, o_ic, smax, sden, sums);
    k_segprob<<<(NB * KK + 255) / 256, 256, 0, stream>>>(sums, o_np, o_sp);
}

// Round 3
// 359.745 us; speedup vs baseline: 1.6561x; 1.3587x over previous
//
#include <hip/hip_runtime.h>
#include <stdint.h>

#define NB 2
#define NC 34
#define HH 512
#define WW 1024
#define HWW (HH*WW)
#define KK 200
#define CAP 32768
#define MCAP 4096

// NMS tiling
#define TW 128
#define TH 16
#define HALO 3

// ---------------------------------------------------------------- init ws
__global__ void __launch_bounds__(256) k_init(uint32_t* cnt, uint32_t* counts, float* sums) {
    int t = blockIdx.x * 256 + threadIdx.x;
    if (t < NB) cnt[t] = 0u;
    if (t < NB * (KK + 1) * NC) counts[t] = 0u;
    if (t < NB * (KK + 1)) sums[t] = 0.f;
}

// ------------------------------------------- per-pixel argmax + softmax stats
__global__ void __launch_bounds__(256) k_seg(const float* __restrict__ logits,
                                             float* __restrict__ segs_out,
                                             float* __restrict__ smax,
                                             float* __restrict__ sden,
                                             int use_stats) {
    int t = blockIdx.x * 256 + threadIdx.x;   // t < NB*HWW/2
    if (t >= NB * HWW / 2) return;
    int p = t * 2;
    int b = p / HWW, r = p - b * HWW;
    const float* base = logits + (size_t)b * NC * HWW + r;
    float2 v[NC];
    float m0 = -3e38f, m1 = -3e38f;
    int a0 = 0, a1 = 0;
#pragma unroll
    for (int c = 0; c < NC; ++c) {
        v[c] = *(const float2*)(base + (size_t)c * HWW);
        if (v[c].x > m0) { m0 = v[c].x; a0 = c; }
        if (v[c].y > m1) { m1 = v[c].y; a1 = c; }
    }
    float s0 = 0.f, s1 = 0.f;
#pragma unroll
    for (int c = 0; c < NC; ++c) {
        s0 += __expf(v[c].x - m0);
        s1 += __expf(v[c].y - m1);
    }
    *(float2*)(segs_out + p) = make_float2((float)a0, (float)a1);
    if (use_stats) {
        *(float2*)(smax + p) = make_float2(m0, m1);
        *(float2*)(sden + p) = make_float2(s0, s1);
    }
}

// ------------------------------------------------- NMS: separable 7x7 max via LDS
__global__ void __launch_bounds__(256) k_nms(const float* __restrict__ cmap,
                                             uint64_t* __restrict__ cand,
                                             uint32_t* __restrict__ cnt) {
    __shared__ float sIn[TH + 2 * HALO][TW + 2 * HALO];   // 22 x 134
    __shared__ float sH[TH + 2 * HALO][TW];               // 22 x 128
    int t = blockIdx.x;
    int bx = t & (WW / TW - 1);          // 0..7
    int by = (t >> 3) & (HH / TH - 1);   // 0..31
    int b = t >> 8;                      // 0..NB-1
    int tid = threadIdx.x;
    const float* bb = cmap + (size_t)b * HWW;

    const int LW = TW + 2 * HALO;                 // 134
    const int LH = TH + 2 * HALO;                 // 22
    for (int idx = tid; idx < LW * LH; idx += 256) {
        int r = idx / LW, c = idx - r * LW;
        int gh = by * TH + r - HALO;
        int gw = bx * TW + c - HALO;
        float v = -3e38f;
        if (gh >= 0 && gh < HH && gw >= 0 && gw < WW) v = bb[gh * WW + gw];
        sIn[r][c] = v;
    }
    __syncthreads();

    // horizontal 1x7 max
    for (int idx = tid; idx < LH * TW; idx += 256) {
        int r = idx / TW, c = idx - r * TW;
        float m = fmaxf(fmaxf(fmaxf(sIn[r][c], sIn[r][c + 1]),
                              fmaxf(sIn[r][c + 2], sIn[r][c + 3])),
                        fmaxf(fmaxf(sIn[r][c + 4], sIn[r][c + 5]), sIn[r][c + 6]));
        sH[r][c] = m;
    }
    __syncthreads();

    // vertical 7x1 max + candidate test
    for (int idx = tid; idx < TH * TW; idx += 256) {
        int r = idx >> 7, c = idx & (TW - 1);
        float cv = sIn[r + HALO][c + HALO];
        float m = fmaxf(fmaxf(fmaxf(sH[r][c], sH[r + 1][c]),
                              fmaxf(sH[r + 2][c], sH[r + 3][c])),
                        fmaxf(fmaxf(sH[r + 4][c], sH[r + 5][c]), sH[r + 6][c]));
        if (m > 0.1f && cv == m) {
            int gh = by * TH + r;
            int gw = bx * TW + c;
            uint32_t rr = (uint32_t)(gh * WW + gw);
            uint32_t pos = atomicAdd(&cnt[b], 1u);
            if (pos < CAP) {
                uint32_t bits = __float_as_uint(cv);
                cand[(size_t)b * CAP + pos] =
                    ((uint64_t)bits << 32) | (uint64_t)(0xFFFFFFFFu - rr);
            }
        }
    }
}

// ------------------------- exact top-K: radix-select on float bits + exact rank
__global__ void __launch_bounds__(256) k_topk(const uint64_t* __restrict__ cand,
                                              const uint32_t* __restrict__ cnt,
                                              float* __restrict__ probs_out,
                                              float* __restrict__ cxy) {
    int b = blockIdx.x;
    int tid = threadIdx.x;
    __shared__ uint32_t shist[256];
    __shared__ uint64_t lkey[MCAP];
    __shared__ uint32_t lM, sPrefix, sNeed;

    if (tid < KK) {
        probs_out[b * KK + tid] = 0.f;
        cxy[(b * KK + tid) * 2]     = 1e19f;  // invalid -> huge coords -> inf dist
        cxy[(b * KK + tid) * 2 + 1] = 1e19f;
    }
    if (tid == 0) { lM = 0u; sPrefix = 0u; sNeed = KK; }
    uint32_t N = cnt[b];
    if (N > CAP) N = CAP;
    __syncthreads();

    uint32_t T = 0u;
    if (N > KK) {
        const uint64_t* cb = cand + (size_t)b * CAP;
        for (int shift = 24; shift >= 0; shift -= 8) {
            shist[tid] = 0u;
            __syncthreads();
            uint32_t prefix = sPrefix;
            uint32_t mask = (shift == 24) ? 0u : (0xFFFFFFFFu << (shift + 8));
            for (uint32_t i = tid; i < N; i += 256) {
                uint32_t k32 = (uint32_t)(cb[i] >> 32);
                if ((k32 & mask) == prefix)
                    atomicAdd(&shist[(k32 >> shift) & 255u], 1u);
            }
            __syncthreads();
            if (tid == 0) {
                uint32_t need = sNeed, cum = 0u;
                int sel = 0;
                for (int d = 255; d >= 0; --d) {
                    uint32_t c = shist[d];
                    if (cum + c >= need) { sel = d; sNeed = need - cum; break; }
                    cum += c;
                }
                sPrefix = prefix | ((uint32_t)sel << shift);
            }
            __syncthreads();
        }
        T = sPrefix;   // exact float-bit pattern of the KK-th largest value
    }

    // collect all candidates with value-bits >= T (M = KK + exact-value ties)
    {
        const uint64_t* cb = cand + (size_t)b * CAP;
        for (uint32_t i = tid; i < N; i += 256) {
            uint64_t kk = cb[i];
            if ((uint32_t)(kk >> 32) >= T) {
                uint32_t pos = atomicAdd(&lM, 1u);
                if (pos < MCAP) lkey[pos] = kk;
            }
        }
    }
    __syncthreads();
    uint32_t M = lM;
    if (M > MCAP) M = MCAP;
    // exact global rank (desc value, asc index via ~idx in low bits)
    for (uint32_t i = tid; i < M; i += 256) {
        uint64_t kk = lkey[i];
        uint32_t rank = 0;
        for (uint32_t j = 0; j < M; ++j) rank += (lkey[j] > kk) ? 1u : 0u;
        if (rank < KK) {
            uint32_t bits = (uint32_t)(kk >> 32);
            uint32_t idx = 0xFFFFFFFFu - (uint32_t)(kk & 0xFFFFFFFFull);
            probs_out[b * KK + rank] = __uint_as_float(bits);
            cxy[(b * KK + rank) * 2]     = (float)(idx % WW);
            cxy[(b * KK + rank) * 2 + 1] = (float)(idx / WW);
        }
    }
}

// ---------------------------------------- closest-center argmin + counts hist
__global__ void __launch_bounds__(256) k_assign(const float* __restrict__ reg,
                                                const float* __restrict__ cxy,
                                                const float* __restrict__ segsf,
                                                float* __restrict__ closest_out,
                                                uint32_t* __restrict__ counts) {
    __shared__ float2 cc[KK];
    int p0 = blockIdx.x * 256;
    int b = p0 / HWW;
    int tid = threadIdx.x;
    if (tid < KK) cc[tid] = ((const float2*)cxy)[b * KK + tid];
    __syncthreads();
    int p = p0 + tid;
    int r = p - b * HWW;
    int h = r / WW, w = r - h * WW;
    float rx = reg[(size_t)b * 2 * HWW + r];
    float ry = reg[(size_t)b * 2 * HWW + HWW + r];
    float px = (float)(w + 1) - rx;
    float py = (float)(h + 1) - ry;
    float best = __builtin_inff();
    int bk = 0;
#pragma unroll 4
    for (int k = 0; k < KK; ++k) {
        float2 c = cc[k];
        float dx = __fsub_rn(px, c.x);
        float dy = __fsub_rn(py, c.y);
        float d2 = __fadd_rn(__fmul_rn(dx, dx), __fmul_rn(dy, dy));  // no fma, match ref
        if (d2 < best) { best = d2; bk = k; }   // strict < : first-occurrence argmin
    }
    closest_out[p] = (float)(bk + 1);
    int seg = (int)segsf[p];
    if (seg >= 24 && seg <= 33) {
        atomicAdd(&counts[(b * (KK + 1) + (bk + 1)) * NC + seg], 1u);
    }
}

// ---------------------------------------- per-instance majority class, n, valid
__global__ void __launch_bounds__(256) k_inst(const uint32_t* __restrict__ counts,
                                              const float* __restrict__ probs_out,
                                              float* __restrict__ ic_out,
                                              float* __restrict__ np_out,
                                              float* __restrict__ va_out) {
    int t = blockIdx.x * 256 + threadIdx.x;
    if (t >= NB * KK) return;
    int b = t / KK, k = t - b * KK;
    const uint32_t* row = counts + (size_t)(b * (KK + 1) + (k + 1)) * NC;
    uint32_t n = 0, mx = 0;
    int am = 0;
#pragma unroll
    for (int c = 0; c < NC; ++c) {
        uint32_t x = row[c];
        n += x;
        if (x > mx) { mx = x; am = c; }   // first-occurrence argmax
    }
    ic_out[t] = (float)am;
    np_out[t] = (float)n;
    va_out[t] = (n > 0u && probs_out[t] > 0.f) ? 1.f : 0.f;
}

// ---------------------------------------- per-instance softmax-prob sums
template <int USE_STATS>
__global__ void __launch_bounds__(256) k_sums(const float* __restrict__ logits,
                                              const float* __restrict__ segsf,
                                              const float* __restrict__ closestf,
                                              const float* __restrict__ icf,
                                              const float* __restrict__ smax,
                                              const float* __restrict__ sden,
                                              float* __restrict__ sums) {
    __shared__ int ic_l[KK];
    __shared__ float psum[KK + 1];
    int tid = threadIdx.x;
    int p0 = blockIdx.x * 256;
    int b = p0 / HWW;
    if (tid < KK) ic_l[tid] = (int)icf[b * KK + tid];
    if (tid < KK + 1) psum[tid] = 0.f;
    __syncthreads();
    int p = p0 + tid;
    int r = p - b * HWW;
    int seg = (int)segsf[p];
    if (seg >= 24 && seg <= 33) {
        int cl = (int)closestf[p];
        int ic = ic_l[cl - 1];
        const float* base = logits + (size_t)b * NC * HWW + r;
        float pr;
        if (USE_STATS) {
            float vmax = smax[p], den = sden[p];
            float lv = base[(size_t)ic * HWW];
            pr = __expf(lv - vmax) / den;
        } else {
            float v[NC];
            float vmax = -3e38f, lv = 0.f;
#pragma unroll
            for (int c = 0; c < NC; ++c) {
                v[c] = base[(size_t)c * HWW];
                vmax = fmaxf(vmax, v[c]);
                if (c == ic) lv = v[c];
            }
            float s = 0.f;
#pragma unroll
            for (int c = 0; c < NC; ++c) s += __expf(v[c] - vmax);
            pr = __expf(lv - vmax) / s;
        }
        atomicAdd(&psum[cl], pr);
    }
    __syncthreads();
    if (tid < KK + 1) {
        float x = psum[tid];
        if (x != 0.f) atomicAdd(&sums[b * (KK + 1) + tid], x);
    }
}

// ---------------------------------------- final seg_prob
__global__ void __launch_bounds__(256) k_segprob(const float* __restrict__ sums,
                                                 const float* __restrict__ np_out,
                                                 float* __restrict__ sp_out) {
    int t = blockIdx.x * 256 + threadIdx.x;
    if (t >= NB * KK) return;
    int b = t / KK, k = t - b * KK;
    float n = np_out[t];
    float s = sums[b * (KK + 1) + k + 1];
    sp_out[t] = (n > 0.f) ? (s / n) : 0.f;
}

extern "C" void kernel_launch(void* const* d_in, const int* in_sizes, int n_in,
                              void* d_out, int out_size, void* d_ws, size_t ws_size,
                              hipStream_t stream) {
    const float* logits = (const float*)d_in[0];
    const float* cmap   = (const float*)d_in[1];
    const float* reg    = (const float*)d_in[2];
    float* out = (float*)d_out;
    float* o_ic   = out;
    float* o_prob = out + NB * KK;
    float* o_sp   = out + 2 * NB * KK;
    float* o_np   = out + 3 * NB * KK;
    float* o_va   = out + 4 * NB * KK;
    float* o_segs = out + 5 * NB * KK;
    float* o_clo  = out + 5 * NB * KK + NB * HWW;

    char* w = (char*)d_ws;
    size_t off = 0;
    auto alloc = [&](size_t bytes) {
        off = (off + 15) & ~((size_t)15);
        void* p = w + off;
        off += bytes;
        return p;
    };
    uint64_t* cand   = (uint64_t*)alloc(sizeof(uint64_t) * NB * CAP);
    uint32_t* cnt    = (uint32_t*)alloc(sizeof(uint32_t) * NB);
    uint32_t* counts = (uint32_t*)alloc(sizeof(uint32_t) * NB * (KK + 1) * NC);
    float* sums      = (float*)alloc(sizeof(float) * NB * (KK + 1));
    float* cxy       = (float*)alloc(sizeof(float) * NB * KK * 2);
    size_t base_need = (off + 15) & ~((size_t)15);
    float* smax = (float*)(w + base_need);
    float* sden = smax + (size_t)NB * HWW;
    int use_stats = (base_need + sizeof(float) * 2 * (size_t)NB * HWW) <= ws_size ? 1 : 0;

    k_init<<<(NB * (KK + 1) * NC + 255) / 256, 256, 0, stream>>>(cnt, counts, sums);
    k_seg<<<NB * HWW / 2 / 256, 256, 0, stream>>>(logits, o_segs, smax, sden, use_stats);
    k_nms<<<NB * (HH / TH) * (WW / TW), 256, 0, stream>>>(cmap, cand, cnt);
    k_topk<<<NB, 256, 0, stream>>>(cand, cnt, o_prob, cxy);
    k_assign<<<NB * HWW / 256, 256, 0, stream>>>(reg, cxy, o_segs, o_clo, counts);
    k_inst<<<(NB * KK + 255) / 256, 256, 0, stream>>>(counts, o_prob, o_ic, o_np, o_va);
    if (use_stats)
        k_sums<1><<<NB * HWW / 256, 256, 0, stream>>>(logits, o_segs, o_clo, o_ic, smax, sden, sums);
    else
        k_sums<0><<<NB * HWW / 256, 256, 0, stream>>>(logits, o_segs, o_clo, o_ic, smax, sden, sums);
    k_segprob<<<(NB * KK + 255) / 256, 256, 0, stream>>>(sums, o_np, o_sp);
}

// Round 4
// 227.902 us; speedup vs baseline: 2.6141x; 1.5785x over previous
//
#include <hip/hip_runtime.h>
#include <stdint.h>

#define NB 2
#define NC 34
#define HH 512
#define WW 1024
#define HWW (HH*WW)
#define KK 200
#define CAP 32768
#define MCAP 4096
#define LCAP 512

// NMS tiling
#define TW 128
#define TH 16
#define HALO 3

// ---------------------------------------------------------------- init ws
__global__ void __launch_bounds__(256) k_init(uint32_t* cnt, uint32_t* counts, float* sums) {
    int t = blockIdx.x * 256 + threadIdx.x;
    if (t < NB) cnt[t] = 0u;
    if (t < NB * (KK + 1) * NC) counts[t] = 0u;
    if (t < NB * (KK + 1)) sums[t] = 0.f;
}

// ------------------------------------------- per-pixel argmax + softmax stats
__global__ void __launch_bounds__(256) k_seg(const float* __restrict__ logits,
                                             float* __restrict__ segs_out,
                                             float* __restrict__ smax,
                                             float* __restrict__ sden,
                                             int use_stats) {
    int t = blockIdx.x * 256 + threadIdx.x;   // t < NB*HWW/2
    if (t >= NB * HWW / 2) return;
    int p = t * 2;
    int b = p / HWW, r = p - b * HWW;
    const float* base = logits + (size_t)b * NC * HWW + r;
    float2 v[NC];
    float m0 = -3e38f, m1 = -3e38f;
    int a0 = 0, a1 = 0;
#pragma unroll
    for (int c = 0; c < NC; ++c) {
        v[c] = *(const float2*)(base + (size_t)c * HWW);
        if (v[c].x > m0) { m0 = v[c].x; a0 = c; }
        if (v[c].y > m1) { m1 = v[c].y; a1 = c; }
    }
    float s0 = 0.f, s1 = 0.f;
#pragma unroll
    for (int c = 0; c < NC; ++c) {
        s0 += __expf(v[c].x - m0);
        s1 += __expf(v[c].y - m1);
    }
    *(float2*)(segs_out + p) = make_float2((float)a0, (float)a1);
    if (use_stats) {
        *(float2*)(smax + p) = make_float2(m0, m1);
        *(float2*)(sden + p) = make_float2(s0, s1);
    }
}

// ----------------- NMS: separable 7x7 max via LDS + per-block candidate compaction
__global__ void __launch_bounds__(256) k_nms(const float* __restrict__ cmap,
                                             uint64_t* __restrict__ cand,
                                             uint32_t* __restrict__ cnt) {
    __shared__ float sIn[TH + 2 * HALO][TW + 2 * HALO];   // 22 x 134
    __shared__ float sH[TH + 2 * HALO][TW];               // 22 x 128
    __shared__ uint64_t lc[LCAP];
    __shared__ uint32_t lcnt, gbase;
    int t = blockIdx.x;
    int bx = t & (WW / TW - 1);          // 0..7
    int by = (t >> 3) & (HH / TH - 1);   // 0..31
    int b = t >> 8;                      // 0..NB-1
    int tid = threadIdx.x;
    const float* bb = cmap + (size_t)b * HWW;
    if (tid == 0) lcnt = 0u;

    const int LW = TW + 2 * HALO;                 // 134
    const int LH = TH + 2 * HALO;                 // 22
    for (int idx = tid; idx < LW * LH; idx += 256) {
        int r = idx / LW, c = idx - r * LW;
        int gh = by * TH + r - HALO;
        int gw = bx * TW + c - HALO;
        float v = -3e38f;
        if (gh >= 0 && gh < HH && gw >= 0 && gw < WW) v = bb[gh * WW + gw];
        sIn[r][c] = v;
    }
    __syncthreads();

    // horizontal 1x7 max
    for (int idx = tid; idx < LH * TW; idx += 256) {
        int r = idx / TW, c = idx - r * TW;
        float m = fmaxf(fmaxf(fmaxf(sIn[r][c], sIn[r][c + 1]),
                              fmaxf(sIn[r][c + 2], sIn[r][c + 3])),
                        fmaxf(fmaxf(sIn[r][c + 4], sIn[r][c + 5]), sIn[r][c + 6]));
        sH[r][c] = m;
    }
    __syncthreads();

    // vertical 7x1 max + candidate test -> LDS compaction
    for (int idx = tid; idx < TH * TW; idx += 256) {
        int r = idx >> 7, c = idx & (TW - 1);
        float cv = sIn[r + HALO][c + HALO];
        float m = fmaxf(fmaxf(fmaxf(sH[r][c], sH[r + 1][c]),
                              fmaxf(sH[r + 2][c], sH[r + 3][c])),
                        fmaxf(fmaxf(sH[r + 4][c], sH[r + 5][c]), sH[r + 6][c]));
        if (m > 0.1f && cv == m) {
            int gh = by * TH + r;
            int gw = bx * TW + c;
            uint32_t rr = (uint32_t)(gh * WW + gw);
            uint32_t pos = atomicAdd(&lcnt, 1u);   // LDS atomic: per-CU, fast
            if (pos < LCAP)
                lc[pos] = ((uint64_t)__float_as_uint(cv) << 32) |
                          (uint64_t)(0xFFFFFFFFu - rr);
        }
    }
    __syncthreads();
    uint32_t n = lcnt;
    if (n > LCAP) n = LCAP;
    if (tid == 0 && n) gbase = atomicAdd(&cnt[b], n);   // ONE global atomic per block
    __syncthreads();
    for (uint32_t i = tid; i < n; i += 256) {
        uint32_t pos = gbase + i;
        if (pos < CAP) cand[(size_t)b * CAP + pos] = lc[i];
    }
}

// ------------------------- exact top-K: radix-select on float bits + exact rank
__global__ void __launch_bounds__(256) k_topk(const uint64_t* __restrict__ cand,
                                              const uint32_t* __restrict__ cnt,
                                              float* __restrict__ probs_out,
                                              float* __restrict__ cxy) {
    int b = blockIdx.x;
    int tid = threadIdx.x;
    __shared__ uint32_t shist[256];
    __shared__ uint64_t lkey[MCAP];
    __shared__ uint32_t lM, sPrefix, sNeed;

    if (tid < KK) {
        probs_out[b * KK + tid] = 0.f;
        cxy[(b * KK + tid) * 2]     = 1e19f;  // invalid -> huge coords -> inf dist
        cxy[(b * KK + tid) * 2 + 1] = 1e19f;
    }
    if (tid == 0) { lM = 0u; sPrefix = 0u; sNeed = KK; }
    uint32_t N = cnt[b];
    if (N > CAP) N = CAP;
    __syncthreads();

    uint32_t T = 0u;
    if (N > KK) {
        const uint64_t* cb = cand + (size_t)b * CAP;
        for (int shift = 24; shift >= 0; shift -= 8) {
            shist[tid] = 0u;
            __syncthreads();
            uint32_t prefix = sPrefix;
            uint32_t mask = (shift == 24) ? 0u : (0xFFFFFFFFu << (shift + 8));
            for (uint32_t i = tid; i < N; i += 256) {
                uint32_t k32 = (uint32_t)(cb[i] >> 32);
                if ((k32 & mask) == prefix)
                    atomicAdd(&shist[(k32 >> shift) & 255u], 1u);
            }
            __syncthreads();
            if (tid == 0) {
                uint32_t need = sNeed, cum = 0u;
                int sel = 0;
                for (int d = 255; d >= 0; --d) {
                    uint32_t c = shist[d];
                    if (cum + c >= need) { sel = d; sNeed = need - cum; break; }
                    cum += c;
                }
                sPrefix = prefix | ((uint32_t)sel << shift);
            }
            __syncthreads();
        }
        T = sPrefix;   // exact float-bit pattern of the KK-th largest value
    }

    // collect all candidates with value-bits >= T (M = KK + exact-value ties)
    {
        const uint64_t* cb = cand + (size_t)b * CAP;
        for (uint32_t i = tid; i < N; i += 256) {
            uint64_t kk = cb[i];
            if ((uint32_t)(kk >> 32) >= T) {
                uint32_t pos = atomicAdd(&lM, 1u);
                if (pos < MCAP) lkey[pos] = kk;
            }
        }
    }
    __syncthreads();
    uint32_t M = lM;
    if (M > MCAP) M = MCAP;
    // exact global rank (desc value, asc index via ~idx in low bits)
    for (uint32_t i = tid; i < M; i += 256) {
        uint64_t kk = lkey[i];
        uint32_t rank = 0;
        for (uint32_t j = 0; j < M; ++j) rank += (lkey[j] > kk) ? 1u : 0u;
        if (rank < KK) {
            uint32_t bits = (uint32_t)(kk >> 32);
            uint32_t idx = 0xFFFFFFFFu - (uint32_t)(kk & 0xFFFFFFFFull);
            probs_out[b * KK + rank] = __uint_as_float(bits);
            cxy[(b * KK + rank) * 2]     = (float)(idx % WW);
            cxy[(b * KK + rank) * 2 + 1] = (float)(idx / WW);
        }
    }
}

// ---------------------------------------- closest-center argmin + counts hist
__global__ void __launch_bounds__(256) k_assign(const float* __restrict__ reg,
                                                const float* __restrict__ cxy,
                                                const float* __restrict__ segsf,
                                                float* __restrict__ closest_out,
                                                uint32_t* __restrict__ counts) {
    __shared__ float2 cc[KK];
    int p0 = blockIdx.x * 256;
    int b = p0 / HWW;
    int tid = threadIdx.x;
    if (tid < KK) cc[tid] = ((const float2*)cxy)[b * KK + tid];
    __syncthreads();
    int p = p0 + tid;
    int r = p - b * HWW;
    int h = r / WW, w = r - h * WW;
    float rx = reg[(size_t)b * 2 * HWW + r];
    float ry = reg[(size_t)b * 2 * HWW + HWW + r];
    float px = (float)(w + 1) - rx;
    float py = (float)(h + 1) - ry;
    float best = __builtin_inff();
    int bk = 0;
#pragma unroll 4
    for (int k = 0; k < KK; ++k) {
        float2 c = cc[k];
        float dx = __fsub_rn(px, c.x);
        float dy = __fsub_rn(py, c.y);
        float d2 = __fadd_rn(__fmul_rn(dx, dx), __fmul_rn(dy, dy));  // no fma, match ref
        if (d2 < best) { best = d2; bk = k; }   // strict < : first-occurrence argmin
    }
    closest_out[p] = (float)(bk + 1);
    int seg = (int)segsf[p];
    if (seg >= 24 && seg <= 33) {
        atomicAdd(&counts[(b * (KK + 1) + (bk + 1)) * NC + seg], 1u);
    }
}

// ---------------------------------------- per-instance majority class, n, valid
__global__ void __launch_bounds__(256) k_inst(const uint32_t* __restrict__ counts,
                                              const float* __restrict__ probs_out,
                                              float* __restrict__ ic_out,
                                              float* __restrict__ np_out,
                                              float* __restrict__ va_out) {
    int t = blockIdx.x * 256 + threadIdx.x;
    if (t >= NB * KK) return;
    int b = t / KK, k = t - b * KK;
    const uint32_t* row = counts + (size_t)(b * (KK + 1) + (k + 1)) * NC;
    uint32_t n = 0, mx = 0;
    int am = 0;
#pragma unroll
    for (int c = 0; c < NC; ++c) {
        uint32_t x = row[c];
        n += x;
        if (x > mx) { mx = x; am = c; }   // first-occurrence argmax
    }
    ic_out[t] = (float)am;
    np_out[t] = (float)n;
    va_out[t] = (n > 0u && probs_out[t] > 0.f) ? 1.f : 0.f;
}

// ---------------------------------------- per-instance softmax-prob sums
template <int USE_STATS>
__global__ void __launch_bounds__(256) k_sums(const float* __restrict__ logits,
                                              const float* __restrict__ segsf,
                                              const float* __restrict__ closestf,
                                              const float* __restrict__ icf,
                                              const float* __restrict__ smax,
                                              const float* __restrict__ sden,
                                              float* __restrict__ sums) {
    __shared__ int ic_l[KK];
    __shared__ float psum[KK + 1];
    int tid = threadIdx.x;
    int p0 = blockIdx.x * 256;
    int b = p0 / HWW;
    if (tid < KK) ic_l[tid] = (int)icf[b * KK + tid];
    if (tid < KK + 1) psum[tid] = 0.f;
    __syncthreads();
    int p = p0 + tid;
    int r = p - b * HWW;
    int seg = (int)segsf[p];
    if (seg >= 24 && seg <= 33) {
        int cl = (int)closestf[p];
        int ic = ic_l[cl - 1];
        const float* base = logits + (size_t)b * NC * HWW + r;
        float pr;
        if (USE_STATS) {
            float vmax = smax[p], den = sden[p];
            float lv = base[(size_t)ic * HWW];
            pr = __expf(lv - vmax) / den;
        } else {
            float v[NC];
            float vmax = -3e38f, lv = 0.f;
#pragma unroll
            for (int c = 0; c < NC; ++c) {
                v[c] = base[(size_t)c * HWW];
                vmax = fmaxf(vmax, v[c]);
                if (c == ic) lv = v[c];
            }
            float s = 0.f;
#pragma unroll
            for (int c = 0; c < NC; ++c) s += __expf(v[c] - vmax);
            pr = __expf(lv - vmax) / s;
        }
        atomicAdd(&psum[cl], pr);
    }
    __syncthreads();
    if (tid < KK + 1) {
        float x = psum[tid];
        if (x != 0.f) atomicAdd(&sums[b * (KK + 1) + tid], x);
    }
}

// ---------------------------------------- final seg_prob
__global__ void __launch_bounds__(256) k_segprob(const float* __restrict__ sums,
                                                 const float* __restrict__ np_out,
                                                 float* __restrict__ sp_out) {
    int t = blockIdx.x * 256 + threadIdx.x;
    if (t >= NB * KK) return;
    int b = t / KK, k = t - b * KK;
    float n = np_out[t];
    float s = sums[b * (KK + 1) + k + 1];
    sp_out[t] = (n > 0.f) ? (s / n) : 0.f;
}

extern "C" void kernel_launch(void* const* d_in, const int* in_sizes, int n_in,
                              void* d_out, int out_size, void* d_ws, size_t ws_size,
                              hipStream_t stream) {
    const float* logits = (const float*)d_in[0];
    const float* cmap   = (const float*)d_in[1];
    const float* reg    = (const float*)d_in[2];
    float* out = (float*)d_out;
    float* o_ic   = out;
    float* o_prob = out + NB * KK;
    float* o_sp   = out + 2 * NB * KK;
    float* o_np   = out + 3 * NB * KK;
    float* o_va   = out + 4 * NB * KK;
    float* o_segs = out + 5 * NB * KK;
    float* o_clo  = out + 5 * NB * KK + NB * HWW;

    char* w = (char*)d_ws;
    size_t off = 0;
    auto alloc = [&](size_t bytes) {
        off = (off + 15) & ~((size_t)15);
        void* p = w + off;
        off += bytes;
        return p;
    };
    uint64_t* cand   = (uint64_t*)alloc(sizeof(uint64_t) * NB * CAP);
    uint32_t* cnt    = (uint32_t*)alloc(sizeof(uint32_t) * NB);
    uint32_t* counts = (uint32_t*)alloc(sizeof(uint32_t) * NB * (KK + 1) * NC);
    float* sums      = (float*)alloc(sizeof(float) * NB * (KK + 1));
    float* cxy       = (float*)alloc(sizeof(float) * NB * KK * 2);
    size_t base_need = (off + 15) & ~((size_t)15);
    float* smax = (float*)(w + base_need);
    float* sden = smax + (size_t)NB * HWW;
    int use_stats = (base_need + sizeof(float) * 2 * (size_t)NB * HWW) <= ws_size ? 1 : 0;

    k_init<<<(NB * (KK + 1) * NC + 255) / 256, 256, 0, stream>>>(cnt, counts, sums);
    k_seg<<<NB * HWW / 2 / 256, 256, 0, stream>>>(logits, o_segs, smax, sden, use_stats);
    k_nms<<<NB * (HH / TH) * (WW / TW), 256, 0, stream>>>(cmap, cand, cnt);
    k_topk<<<NB, 256, 0, stream>>>(cand, cnt, o_prob, cxy);
    k_assign<<<NB * HWW / 256, 256, 0, stream>>>(reg, cxy, o_segs, o_clo, counts);
    k_inst<<<(NB * KK + 255) / 256, 256, 0, stream>>>(counts, o_prob, o_ic, o_np, o_va);
    if (use_stats)
        k_sums<1><<<NB * HWW / 256, 256, 0, stream>>>(logits, o_segs, o_clo, o_ic, smax, sden, sums);
    else
        k_sums<0><<<NB * HWW / 256, 256, 0, stream>>>(logits, o_segs, o_clo, o_ic, smax, sden, sums);
    k_segprob<<<(NB * KK + 255) / 256, 256, 0, stream>>>(sums, o_np, o_sp);
}